// Round 1
// baseline (232.683 us; speedup 1.0000x reference)
//
#include <hip/hip_runtime.h>

// Problem constants (from reference): B=256 batch, L=20 decode len,
// V=9488 vocab, S=18 target seq len. t_len = L-1 = 19.
constexpr int kB = 256;
constexpr int kL = 20;
constexpr int kV = 9488;
constexpr int kS = 18;
constexpr int kT = kL - 1;  // 19

// One block of 256 threads; thread b handles batch row b.
// loss = -(sum_{b,t} logp[b,t]*mask[b,t] / sum mask) * max(reward-reward1, 1)
//   logp[b,t] = input[b, t+1, tgt[b,t]],  tgt = [target | 0][:, :19]
//   mask[b,t] = (inclusive cumulative count of zeros in tgt[b,0..t]) <= 1
__global__ __launch_bounds__(256) void scst_loss_kernel(
    const float* __restrict__ inp,      // [B, L, V] fp32
    const int* __restrict__ target,     // [B, S] int32
    const float* __restrict__ reward,   // [1]
    const float* __restrict__ reward1,  // [1]
    float* __restrict__ out)            // [1]
{
    __shared__ int tgt_lds[kB * kS];    // 4608 ints = 18 KiB
    const int tid = threadIdx.x;

    // Coalesced stage of the whole target tensor into LDS.
    #pragma unroll
    for (int i = 0; i < kS; ++i) {
        const int idx = i * kB + tid;   // 0..4607, lane-contiguous
        tgt_lds[idx] = target[idx];
    }
    __syncthreads();

    const int b = tid;
    const float* row = inp + (size_t)b * kL * kV + kV;  // &input[b, 1, 0]

    float sum = 0.0f;
    int cnt = 0;
    int zc = 0;
    #pragma unroll
    for (int t = 0; t < kT; ++t) {
        const int w = (t < kS) ? tgt_lds[b * kS + t] : 0;  // pad col 18 with 0
        zc += (w == 0) ? 1 : 0;                            // inclusive cumsum
        if (zc <= 1) {
            sum += row[(size_t)t * kV + w];
            cnt += 1;
        }
    }

    // Wave (64-lane) butterfly reduction.
    #pragma unroll
    for (int off = 32; off >= 1; off >>= 1) {
        sum += __shfl_down(sum, off, 64);
        cnt += __shfl_down(cnt, off, 64);
    }

    __shared__ float wsum[4];
    __shared__ int   wcnt[4];
    const int wave = tid >> 6;
    const int lane = tid & 63;
    if (lane == 0) { wsum[wave] = sum; wcnt[wave] = cnt; }
    __syncthreads();

    if (tid == 0) {
        const float s = wsum[0] + wsum[1] + wsum[2] + wsum[3];
        const int   c = wcnt[0] + wcnt[1] + wcnt[2] + wcnt[3];
        float rd = reward[0] - reward1[0];
        rd = (rd > 1.0f) ? rd : 1.0f;
        out[0] = -(s / (float)c) * rd;
    }
}

extern "C" void kernel_launch(void* const* d_in, const int* in_sizes, int n_in,
                              void* d_out, int out_size, void* d_ws, size_t ws_size,
                              hipStream_t stream) {
    const float* inp     = (const float*)d_in[0];
    const int*   target  = (const int*)d_in[1];
    const float* reward  = (const float*)d_in[2];
    const float* reward1 = (const float*)d_in[3];
    float* out = (float*)d_out;

    scst_loss_kernel<<<1, 256, 0, stream>>>(inp, target, reward, reward1, out);
}

// Round 2
// 223.962 us; speedup vs baseline: 1.0389x; 1.0389x over previous
//
#include <hip/hip_runtime.h>

// Problem constants (from reference): B=256 batch, L=20 decode len,
// V=9488 vocab, S=18 target seq len. t_len = L-1 = 19.
constexpr int kB = 256;
constexpr int kL = 20;
constexpr int kV = 9488;
constexpr int kS = 18;
constexpr int kT = kL - 1;  // 19

// Kernel A: grid = kT blocks (one per timestep t), 256 threads (one per batch b).
// Spreads the 4864 scattered gather loads across 19 CUs instead of 1, so each
// CU's miss-handling only serializes 256 cacheline fetches.
// Writes per-t partial (sum, count) to ws[t] — plain stores, no init needed.
__global__ __launch_bounds__(256) void scst_partial_kernel(
    const float* __restrict__ inp,      // [B, L, V] fp32
    const int* __restrict__ target,     // [B, S] int32
    float2* __restrict__ partials)      // [kT] (sum, count)
{
    __shared__ int tgt_lds[kB * kS];    // 18 KiB
    const int b = threadIdx.x;
    const int t = blockIdx.x;           // 0..18 (wave-uniform)

    // Coalesced stage of target into LDS.
    #pragma unroll
    for (int i = 0; i < kS; ++i) {
        const int idx = i * kB + b;
        tgt_lds[idx] = target[idx];
    }
    __syncthreads();

    // Gather word index and issue the global load immediately (no control dep).
    const int w = (t < kS) ? tgt_lds[b * kS + t] : 0;   // pad col 18 with 0
    const float val = inp[(size_t)b * kL * kV + (size_t)(t + 1) * kV + w];

    // Inclusive cumulative zero count over tgt[b, 0..t].
    int zc = (t >= kS) ? 1 : 0;                          // pad zero at t=18
    const int imax = (t < kS) ? t : (kS - 1);
    for (int i = 0; i <= imax; ++i)                      // wave-uniform trip count
        zc += (tgt_lds[b * kS + i] == 0) ? 1 : 0;

    const bool m = (zc <= 1);
    float s = m ? val : 0.0f;
    int   c = m ? 1 : 0;

    // 256 -> 1 block reduction: wave butterfly + LDS.
    #pragma unroll
    for (int off = 32; off >= 1; off >>= 1) {
        s += __shfl_down(s, off, 64);
        c += __shfl_down(c, off, 64);
    }
    __shared__ float wsum[4];
    __shared__ int   wcnt[4];
    const int wave = b >> 6;
    const int lane = b & 63;
    if (lane == 0) { wsum[wave] = s; wcnt[wave] = c; }
    __syncthreads();
    if (b == 0) {
        partials[t] = make_float2(wsum[0] + wsum[1] + wsum[2] + wsum[3],
                                  (float)(wcnt[0] + wcnt[1] + wcnt[2] + wcnt[3]));
    }
}

// Kernel B: one wave folds the 19 partials and applies the reward scale.
__global__ __launch_bounds__(64) void scst_final_kernel(
    const float2* __restrict__ partials,
    const float* __restrict__ reward,
    const float* __restrict__ reward1,
    float* __restrict__ out)
{
    const int lane = threadIdx.x;
    float s = 0.0f, c = 0.0f;
    if (lane < kT) {
        const float2 p = partials[lane];
        s = p.x; c = p.y;
    }
    #pragma unroll
    for (int off = 32; off >= 1; off >>= 1) {
        s += __shfl_down(s, off, 64);
        c += __shfl_down(c, off, 64);
    }
    if (lane == 0) {
        float rd = reward[0] - reward1[0];
        rd = (rd > 1.0f) ? rd : 1.0f;
        out[0] = -(s / c) * rd;
    }
}

extern "C" void kernel_launch(void* const* d_in, const int* in_sizes, int n_in,
                              void* d_out, int out_size, void* d_ws, size_t ws_size,
                              hipStream_t stream) {
    const float* inp     = (const float*)d_in[0];
    const int*   target  = (const int*)d_in[1];
    const float* reward  = (const float*)d_in[2];
    const float* reward1 = (const float*)d_in[3];
    float* out = (float*)d_out;
    float2* partials = (float2*)d_ws;   // 19 * 8 B = 152 B of scratch

    scst_partial_kernel<<<kT, 256, 0, stream>>>(inp, target, partials);
    scst_final_kernel<<<1, 64, 0, stream>>>(partials, reward, reward1, out);
}

// Round 3
// 223.520 us; speedup vs baseline: 1.0410x; 1.0020x over previous
//
#include <hip/hip_runtime.h>

// Problem constants (from reference): B=256 batch, L=20 decode len,
// V=9488 vocab, S=18 target seq len. t_len = L-1 = 19.
constexpr int kB = 256;
constexpr int kL = 20;
constexpr int kV = 9488;
constexpr int kS = 18;
constexpr int kT = kL - 1;  // 19

constexpr unsigned kFlagTag = 0xC1DE0000u;  // != 0xAAAAAAAA poison in high 16

// Fused single launch: grid = kT+1 blocks.
//   Blocks 0..18 (t = blockIdx.x): 256 threads, one per batch b. Compute the
//   per-t partial (sum of masked logp, count), publish via agent-scope
//   release store (per-XCD L2s are not coherent -> must use atomics).
//   Block 19: finalizer. Lanes 0..18 of wave 0 acquire-spin on the flag
//   words, fold partials, apply reward scale, write out[0].
// 20 blocks << 256 CUs => all co-resident, spin cannot deadlock.
__global__ __launch_bounds__(256) void scst_fused_kernel(
    const float* __restrict__ inp,      // [B, L, V] fp32
    const int* __restrict__ target,     // [B, S] int32
    const float* __restrict__ reward,   // [1]
    const float* __restrict__ reward1,  // [1]
    float* __restrict__ out,            // [1]
    unsigned* __restrict__ ws)          // [2*kT]: sums bits | flag+count
{
    unsigned* sum_ws  = ws;         // float bits
    unsigned* flag_ws = ws + kT;    // kFlagTag | count

    if (blockIdx.x == kT) {
        // ---- Finalizer block: wave 0 only. ----
        if (threadIdx.x >= 64) return;
        const int lane = threadIdx.x;
        float s = 0.0f;
        int   c = 0;
        if (lane < kT) {
            unsigned v;
            do {
                v = __hip_atomic_load(&flag_ws[lane], __ATOMIC_ACQUIRE,
                                      __HIP_MEMORY_SCOPE_AGENT);
            } while ((v & 0xFFFF0000u) != kFlagTag);
            c = (int)(v & 0xFFFFu);
            const unsigned sb = __hip_atomic_load(&sum_ws[lane], __ATOMIC_RELAXED,
                                                  __HIP_MEMORY_SCOPE_AGENT);
            s = __uint_as_float(sb);
        }
        #pragma unroll
        for (int off = 32; off >= 1; off >>= 1) {
            s += __shfl_down(s, off, 64);
            c += __shfl_down(c, off, 64);
        }
        if (lane == 0) {
            float rd = reward[0] - reward1[0];
            rd = (rd > 1.0f) ? rd : 1.0f;
            out[0] = -(s / (float)c) * rd;
        }
        return;
    }

    // ---- Partial blocks: one timestep t per block, one batch b per thread. ----
    __shared__ int   tgt_lds[kB * kS];  // 18 KiB
    __shared__ float wsum[4];
    __shared__ int   wcnt[4];
    const int b = threadIdx.x;
    const int t = blockIdx.x;           // 0..18 (wave-uniform)

    #pragma unroll
    for (int i = 0; i < kS; ++i) {
        const int idx = i * kB + b;     // coalesced
        tgt_lds[idx] = target[idx];
    }
    __syncthreads();

    // Gather word index, issue the scattered global load immediately.
    const int w = (t < kS) ? tgt_lds[b * kS + t] : 0;   // pad col 18 with 0
    const float val = inp[(size_t)b * kL * kV + (size_t)(t + 1) * kV + w];

    // Inclusive cumulative zero count over tgt[b, 0..t].
    int zc = (t >= kS) ? 1 : 0;                          // pad zero at t=18
    const int imax = (t < kS) ? t : (kS - 1);
    for (int i = 0; i <= imax; ++i)                      // wave-uniform trips
        zc += (tgt_lds[b * kS + i] == 0) ? 1 : 0;

    const bool m = (zc <= 1);
    float s = m ? val : 0.0f;
    int   c = m ? 1 : 0;

    #pragma unroll
    for (int off = 32; off >= 1; off >>= 1) {
        s += __shfl_down(s, off, 64);
        c += __shfl_down(c, off, 64);
    }
    const int wave = b >> 6;
    const int lane = b & 63;
    if (lane == 0) { wsum[wave] = s; wcnt[wave] = c; }
    __syncthreads();

    if (b == 0) {
        const float ts = wsum[0] + wsum[1] + wsum[2] + wsum[3];
        const int   tc = wcnt[0] + wcnt[1] + wcnt[2] + wcnt[3];
        __hip_atomic_store(&sum_ws[t], __float_as_uint(ts), __ATOMIC_RELAXED,
                           __HIP_MEMORY_SCOPE_AGENT);
        __hip_atomic_store(&flag_ws[t], kFlagTag | (unsigned)tc, __ATOMIC_RELEASE,
                           __HIP_MEMORY_SCOPE_AGENT);
    }
}

extern "C" void kernel_launch(void* const* d_in, const int* in_sizes, int n_in,
                              void* d_out, int out_size, void* d_ws, size_t ws_size,
                              hipStream_t stream) {
    const float* inp     = (const float*)d_in[0];
    const int*   target  = (const int*)d_in[1];
    const float* reward  = (const float*)d_in[2];
    const float* reward1 = (const float*)d_in[3];
    float* out = (float*)d_out;
    unsigned* ws = (unsigned*)d_ws;     // 2*19*4 B = 152 B of scratch

    scst_fused_kernel<<<kT + 1, 256, 0, stream>>>(inp, target, reward, reward1,
                                                  out, ws);
}